// Round 1
// baseline (740.156 us; speedup 1.0000x reference)
//
#include <hip/hip_runtime.h>
#include <stdint.h>

#define T_ 4
#define B_ 16
#define C_ 256
#define N_ 1024
#define TBDIM 64
#define M_ELEMS (TBDIM * C_ * N_)   /* 16777216 elements per [TB,C,N] tensor */
#define BCN (B_ * C_ * N_)          /* 4194304 */

/* workspace byte offsets */
#define OFF_Y   0ull
#define OFF_SQ  (3ull * (unsigned long long)M_ELEMS * 4ull)  /* 201326592 */
#define OFF_SK  (OFF_SQ + (unsigned long long)M_ELEMS)
#define OFF_SV  (OFF_SK + (unsigned long long)M_ELEMS)
#define OFF_SA  (OFF_SV + (unsigned long long)M_ELEMS)
#define OFF_KV  (OFF_SA + (unsigned long long)M_ELEMS)
#define OFF_BN  (OFF_KV + 2097152ull)

/* ---- BN coefficient prep: bns[2*i]=scale, bns[2*i+1]=shift; i = br*256+c, br 0..2 = q,k,v; 768+ = p (bias folded) ---- */
__global__ void bn_prep(const float* __restrict__ qg, const float* __restrict__ qb2, const float* __restrict__ qm, const float* __restrict__ qv,
                        const float* __restrict__ kg, const float* __restrict__ kb, const float* __restrict__ km, const float* __restrict__ kvv,
                        const float* __restrict__ vg, const float* __restrict__ vb, const float* __restrict__ vm, const float* __restrict__ vv,
                        const float* __restrict__ pbias,
                        const float* __restrict__ pg, const float* __restrict__ pbt, const float* __restrict__ pm, const float* __restrict__ pv,
                        float* __restrict__ bns) {
  int i = threadIdx.x;  /* 1024 threads */
  int br = i >> 8, c = i & 255;
  const float *g, *bt, *m, *v;
  float bias = 0.f;
  if (br == 0)      { g = qg; bt = qb2; m = qm; v = qv; }
  else if (br == 1) { g = kg; bt = kb;  m = km; v = kvv; }
  else if (br == 2) { g = vg; bt = vb;  m = vm; v = vv; }
  else              { g = pg; bt = pbt; m = pm; v = pv; bias = pbias[c]; }
  float sc = g[c] / sqrtf(v[c] + 1e-5f);
  bns[2 * i] = sc;
  bns[2 * i + 1] = bt[c] + (bias - m[c]) * sc;
}

/* ---- fused q/k/v projection GEMM + BN. grid (8 ntiles, 6 mtiles, 64 tb). tile 128x128, BK=8, 8x8 microtile ---- */
__global__ __launch_bounds__(256) void gemm_qkv_bn(
    const float* __restrict__ x, const float* __restrict__ qw,
    const float* __restrict__ kw, const float* __restrict__ vw,
    const float* __restrict__ bns, float* __restrict__ Y) {
  __shared__ float As[8][128];
  __shared__ float Bs[8][128];
  const int nt = blockIdx.x, mt = blockIdx.y, tb = blockIdx.z;
  const int br = mt >> 1;
  const float* W = (br == 0 ? qw : (br == 1 ? kw : vw)) + (mt & 1) * 128 * 256;
  const float* Xb = x + (size_t)tb * C_ * N_ + nt * 128;
  float* Yb = Y + (size_t)br * M_ELEMS + (size_t)tb * C_ * N_ + (size_t)((mt & 1) * 128) * N_ + nt * 128;
  const int tid = threadIdx.x;
  const int tm = tid >> 4, tn = tid & 15;
  const int lam = tid >> 1, lak = (tid & 1) * 4;
  const int lbk = tid >> 5, lbn = (tid & 31) * 4;
  float acc[8][8];
#pragma unroll
  for (int i = 0; i < 8; ++i)
#pragma unroll
    for (int j = 0; j < 8; ++j) acc[i][j] = 0.f;
  for (int k0 = 0; k0 < 256; k0 += 8) {
    float4 a = *(const float4*)&W[lam * 256 + k0 + lak];
    As[lak + 0][lam] = a.x;
    As[lak + 1][lam] = a.y;
    As[lak + 2][lam] = a.z;
    As[lak + 3][lam] = a.w;
    *(float4*)&Bs[lbk][lbn] = *(const float4*)&Xb[(size_t)(k0 + lbk) * N_ + lbn];
    __syncthreads();
#pragma unroll
    for (int kk = 0; kk < 8; ++kk) {
      float4 a0 = *(const float4*)&As[kk][tm * 4];
      float4 a1 = *(const float4*)&As[kk][64 + tm * 4];
      float4 b0 = *(const float4*)&Bs[kk][tn * 4];
      float4 b1 = *(const float4*)&Bs[kk][64 + tn * 4];
      float am[8] = {a0.x, a0.y, a0.z, a0.w, a1.x, a1.y, a1.z, a1.w};
      float bb[8] = {b0.x, b0.y, b0.z, b0.w, b1.x, b1.y, b1.z, b1.w};
#pragma unroll
      for (int i = 0; i < 8; ++i)
#pragma unroll
        for (int j = 0; j < 8; ++j) acc[i][j] += am[i] * bb[j];
    }
    __syncthreads();
  }
#pragma unroll
  for (int i = 0; i < 8; ++i) {
    int ml = (i < 4) ? (tm * 4 + i) : (64 + tm * 4 + (i - 4));
    int cg = (mt & 1) * 128 + ml;
    float sc = bns[2 * (br * 256 + cg)];
    float sh = bns[2 * (br * 256 + cg) + 1];
    float4 o0 = make_float4(acc[i][0] * sc + sh, acc[i][1] * sc + sh,
                            acc[i][2] * sc + sh, acc[i][3] * sc + sh);
    float4 o1 = make_float4(acc[i][4] * sc + sh, acc[i][5] * sc + sh,
                            acc[i][6] * sc + sh, acc[i][7] * sc + sh);
    *(float4*)&Yb[(size_t)ml * N_ + tn * 4] = o0;
    *(float4*)&Yb[(size_t)ml * N_ + 64 + tn * 4] = o1;
  }
}

/* ---- LIF over t for q,k,v; Y fp32 [3][T,B,C,N] -> spikes u8 (same layout). vth=1.0 ---- */
__global__ __launch_bounds__(256) void lif_qkv(const float* __restrict__ Y, uint8_t* __restrict__ S) {
  int id = blockIdx.x * 256 + threadIdx.x;    /* 3*BCN/4 threads */
  int br = id >> 20;
  size_t e4 = (size_t)(id & 1048575) * 4;
  const float* Yb = Y + (size_t)br * M_ELEMS + e4;
  uint8_t* Sb = S + (size_t)br * M_ELEMS + e4;
  float m0 = 0.f, m1 = 0.f, m2 = 0.f, m3 = 0.f;
#pragma unroll
  for (int t = 0; t < 4; ++t) {
    float4 y = *(const float4*)(Yb + (size_t)t * BCN);
    m0 += (y.x - m0) * 0.5f;
    m1 += (y.y - m1) * 0.5f;
    m2 += (y.z - m2) * 0.5f;
    m3 += (y.w - m3) * 0.5f;
    unsigned s0 = (m0 >= 1.0f), s1 = (m1 >= 1.0f), s2 = (m2 >= 1.0f), s3 = (m3 >= 1.0f);
    *(unsigned*)(Sb + (size_t)t * BCN) = s0 | (s1 << 8) | (s2 << 16) | (s3 << 24);
    if (s0) m0 = 0.f;
    if (s1) m1 = 0.f;
    if (s2) m2 = 0.f;
    if (s3) m3 = 0.f;
  }
}

/* ---- v spikes [T,B,C,N] u8 -> d_out v fp32 [T,B,H,N,D] ---- */
__global__ __launch_bounds__(256) void transpose_v(const uint8_t* __restrict__ SV, float* __restrict__ vout) {
  size_t o4 = ((size_t)blockIdx.x * 256 + threadIdx.x) * 4;
  int dd = (int)(o4 & 31);
  int n = (int)((o4 >> 5) & 1023);
  int h = (int)((o4 >> 15) & 7);
  int tb = (int)(o4 >> 18);
  const uint8_t* src = SV + (size_t)tb * C_ * N_ + (size_t)(h * 32 + dd) * N_ + n;
  *(float4*)(vout + o4) = make_float4((float)src[0], (float)src[(size_t)N_],
                                      (float)src[2 * (size_t)N_], (float)src[3 * (size_t)N_]);
}

/* ---- kv[t,b,h,d,e] = sum_n K[d,n]*V[e,n]; block per (tb,h) ---- */
__global__ __launch_bounds__(256) void kv_gram(const uint8_t* __restrict__ SK,
                                               const uint8_t* __restrict__ SV,
                                               float* __restrict__ KV) {
  __shared__ uint8_t Ks[32 * 132];
  __shared__ uint8_t Vs[32 * 132];
  const int tb = blockIdx.x >> 3, h = blockIdx.x & 7;
  const uint8_t* K = SK + (size_t)tb * C_ * N_ + (size_t)h * 32 * N_;
  const uint8_t* V = SV + (size_t)tb * C_ * N_ + (size_t)h * 32 * N_;
  const int tid = threadIdx.x;
  const int dd = tid >> 3, e0 = (tid & 7) * 4;
  const int lr = tid >> 3, lc = (tid & 7) * 16;
  float a0 = 0.f, a1 = 0.f, a2 = 0.f, a3 = 0.f;
  for (int n0 = 0; n0 < N_; n0 += 128) {
    uint4 kk4 = *(const uint4*)(K + (size_t)lr * N_ + n0 + lc);
    uint4 vv4 = *(const uint4*)(V + (size_t)lr * N_ + n0 + lc);
    unsigned* Kw = (unsigned*)(Ks + lr * 132 + lc);
    unsigned* Vw = (unsigned*)(Vs + lr * 132 + lc);
    Kw[0] = kk4.x; Kw[1] = kk4.y; Kw[2] = kk4.z; Kw[3] = kk4.w;
    Vw[0] = vv4.x; Vw[1] = vv4.y; Vw[2] = vv4.z; Vw[3] = vv4.w;
    __syncthreads();
    for (int n = 0; n < 128; ++n) {
      float kf = (float)Ks[dd * 132 + n];
      a0 += kf * (float)Vs[(e0 + 0) * 132 + n];
      a1 += kf * (float)Vs[(e0 + 1) * 132 + n];
      a2 += kf * (float)Vs[(e0 + 2) * 132 + n];
      a3 += kf * (float)Vs[(e0 + 3) * 132 + n];
    }
    __syncthreads();
  }
  float* o = KV + (size_t)(tb * 8 + h) * 1024 + dd * 32 + e0;
  o[0] = a0; o[1] = a1; o[2] = a2; o[3] = a3;
}

/* ---- fused attn = (Q @ kv)*0.125 then LIF(vth=0.5) -> SA u8 [T,B,C,N]. block: (b,h,n-chunk of 64) ---- */
__global__ __launch_bounds__(256) void attn_lif(const uint8_t* __restrict__ SQ,
                                                const float* __restrict__ KV,
                                                uint8_t* __restrict__ SA) {
  __shared__ float kvs[1024];
  const int bid = blockIdx.x;
  const int nb = bid & 15, h = (bid >> 4) & 7, b = bid >> 7;
  const int n0 = nb * 64;
  const int tid = threadIdx.x;
  const int nl = tid & 63, eg = tid >> 6;
  float mem[8];
#pragma unroll
  for (int j = 0; j < 8; ++j) mem[j] = 0.f;
  for (int t = 0; t < 4; ++t) {
    const float* kvp = KV + (size_t)((t * B_ + b) * 8 + h) * 1024;
    *(float4*)&kvs[tid * 4] = *(const float4*)&kvp[tid * 4];
    __syncthreads();
    const uint8_t* q = SQ + (size_t)(t * B_ + b) * C_ * N_ + (size_t)h * 32 * N_ + n0 + nl;
    float val[8];
#pragma unroll
    for (int j = 0; j < 8; ++j) val[j] = 0.f;
#pragma unroll 4
    for (int dd = 0; dd < 32; ++dd) {
      float qv = (float)q[(size_t)dd * N_];
#pragma unroll
      for (int j = 0; j < 8; ++j) val[j] += qv * kvs[dd * 32 + eg * 8 + j];
    }
    uint8_t* sa = SA + (size_t)(t * B_ + b) * C_ * N_ + (size_t)(h * 32 + eg * 8) * N_ + n0 + nl;
#pragma unroll
    for (int j = 0; j < 8; ++j) {
      float a = val[j] * 0.125f;
      mem[j] += (a - mem[j]) * 0.5f;
      float s = (mem[j] >= 0.5f) ? 1.f : 0.f;
      sa[(size_t)j * N_] = (uint8_t)s;
      mem[j] *= (1.f - s);
    }
    __syncthreads();
  }
}

/* ---- p projection GEMM (+bias+BN) from u8 spikes. grid (8,2,64) ---- */
__global__ __launch_bounds__(256) void gemm_p_bn(
    const uint8_t* __restrict__ SA, const float* __restrict__ pw,
    const float* __restrict__ bns, float* __restrict__ YP) {
  __shared__ float As[8][128];
  __shared__ float Bs[8][128];
  const int nt = blockIdx.x, mt = blockIdx.y, tb = blockIdx.z;
  const float* W = pw + mt * 128 * 256;
  const uint8_t* Sb = SA + (size_t)tb * C_ * N_ + nt * 128;
  float* Yb = YP + (size_t)tb * C_ * N_ + (size_t)(mt * 128) * N_ + nt * 128;
  const int tid = threadIdx.x;
  const int tm = tid >> 4, tn = tid & 15;
  const int lam = tid >> 1, lak = (tid & 1) * 4;
  const int lbk = tid >> 5, lbn = (tid & 31) * 4;
  float acc[8][8];
#pragma unroll
  for (int i = 0; i < 8; ++i)
#pragma unroll
    for (int j = 0; j < 8; ++j) acc[i][j] = 0.f;
  for (int k0 = 0; k0 < 256; k0 += 8) {
    float4 a = *(const float4*)&W[lam * 256 + k0 + lak];
    As[lak + 0][lam] = a.x;
    As[lak + 1][lam] = a.y;
    As[lak + 2][lam] = a.z;
    As[lak + 3][lam] = a.w;
    unsigned u = *(const unsigned*)(Sb + (size_t)(k0 + lbk) * N_ + lbn);
    Bs[lbk][lbn + 0] = (float)(u & 255);
    Bs[lbk][lbn + 1] = (float)((u >> 8) & 255);
    Bs[lbk][lbn + 2] = (float)((u >> 16) & 255);
    Bs[lbk][lbn + 3] = (float)((u >> 24) & 255);
    __syncthreads();
#pragma unroll
    for (int kk = 0; kk < 8; ++kk) {
      float4 a0 = *(const float4*)&As[kk][tm * 4];
      float4 a1 = *(const float4*)&As[kk][64 + tm * 4];
      float4 b0 = *(const float4*)&Bs[kk][tn * 4];
      float4 b1 = *(const float4*)&Bs[kk][64 + tn * 4];
      float am[8] = {a0.x, a0.y, a0.z, a0.w, a1.x, a1.y, a1.z, a1.w};
      float bb[8] = {b0.x, b0.y, b0.z, b0.w, b1.x, b1.y, b1.z, b1.w};
#pragma unroll
      for (int i = 0; i < 8; ++i)
#pragma unroll
        for (int j = 0; j < 8; ++j) acc[i][j] += am[i] * bb[j];
    }
    __syncthreads();
  }
#pragma unroll
  for (int i = 0; i < 8; ++i) {
    int ml = (i < 4) ? (tm * 4 + i) : (64 + tm * 4 + (i - 4));
    int cg = mt * 128 + ml;
    float sc = bns[2 * (768 + cg)];
    float sh = bns[2 * (768 + cg) + 1];
    float4 o0 = make_float4(acc[i][0] * sc + sh, acc[i][1] * sc + sh,
                            acc[i][2] * sc + sh, acc[i][3] * sc + sh);
    float4 o1 = make_float4(acc[i][4] * sc + sh, acc[i][5] * sc + sh,
                            acc[i][6] * sc + sh, acc[i][7] * sc + sh);
    *(float4*)&Yb[(size_t)ml * N_ + tn * 4] = o0;
    *(float4*)&Yb[(size_t)ml * N_ + 64 + tn * 4] = o1;
  }
}

/* ---- final LIF (vth=1.0): YP fp32 [T,B,C,N] -> d_out out fp32 spikes ---- */
__global__ __launch_bounds__(256) void lif_out(const float* __restrict__ YP, float* __restrict__ out) {
  size_t e4 = ((size_t)blockIdx.x * 256 + threadIdx.x) * 4;
  float m0 = 0.f, m1 = 0.f, m2 = 0.f, m3 = 0.f;
#pragma unroll
  for (int t = 0; t < 4; ++t) {
    float4 y = *(const float4*)(YP + (size_t)t * BCN + e4);
    m0 += (y.x - m0) * 0.5f;
    m1 += (y.y - m1) * 0.5f;
    m2 += (y.z - m2) * 0.5f;
    m3 += (y.w - m3) * 0.5f;
    float s0 = (m0 >= 1.0f) ? 1.f : 0.f;
    float s1 = (m1 >= 1.0f) ? 1.f : 0.f;
    float s2 = (m2 >= 1.0f) ? 1.f : 0.f;
    float s3 = (m3 >= 1.0f) ? 1.f : 0.f;
    *(float4*)(out + (size_t)t * BCN + e4) = make_float4(s0, s1, s2, s3);
    m0 *= (1.f - s0);
    m1 *= (1.f - s1);
    m2 *= (1.f - s2);
    m3 *= (1.f - s3);
  }
}

extern "C" void kernel_launch(void* const* d_in, const int* in_sizes, int n_in,
                              void* d_out, int out_size, void* d_ws, size_t ws_size,
                              hipStream_t stream) {
  const float* x   = (const float*)d_in[0];
  /* d_in[1] = res_attn (unused by reference) */
  const float* qw  = (const float*)d_in[2];
  const float* qg  = (const float*)d_in[3];
  const float* qb  = (const float*)d_in[4];
  const float* qm  = (const float*)d_in[5];
  const float* qv  = (const float*)d_in[6];
  const float* kw  = (const float*)d_in[7];
  const float* kg  = (const float*)d_in[8];
  const float* kb  = (const float*)d_in[9];
  const float* km  = (const float*)d_in[10];
  const float* kvv = (const float*)d_in[11];
  const float* vw  = (const float*)d_in[12];
  const float* vg  = (const float*)d_in[13];
  const float* vb  = (const float*)d_in[14];
  const float* vm  = (const float*)d_in[15];
  const float* vv  = (const float*)d_in[16];
  const float* pw  = (const float*)d_in[17];
  const float* pb  = (const float*)d_in[18];
  const float* pg  = (const float*)d_in[19];
  const float* pbt = (const float*)d_in[20];
  const float* pm  = (const float*)d_in[21];
  const float* pv  = (const float*)d_in[22];

  float* out = (float*)d_out;
  float* vout = out + M_ELEMS;

  uint8_t* ws = (uint8_t*)d_ws;
  float* Y    = (float*)(ws + OFF_Y);
  uint8_t* SQ = ws + OFF_SQ;
  uint8_t* SK = ws + OFF_SK;
  uint8_t* SV = ws + OFF_SV;
  uint8_t* SA = ws + OFF_SA;
  float* KV   = (float*)(ws + OFF_KV);
  float* BNS  = (float*)(ws + OFF_BN);

  bn_prep<<<dim3(1), dim3(1024), 0, stream>>>(qg, qb, qm, qv, kg, kb, km, kvv,
                                              vg, vb, vm, vv, pb, pg, pbt, pm, pv, BNS);
  gemm_qkv_bn<<<dim3(8, 6, 64), dim3(256), 0, stream>>>(x, qw, kw, vw, BNS, Y);
  lif_qkv<<<dim3(12288), dim3(256), 0, stream>>>(Y, SQ);
  transpose_v<<<dim3(16384), dim3(256), 0, stream>>>(SV, vout);
  kv_gram<<<dim3(512), dim3(256), 0, stream>>>(SK, SV, KV);
  attn_lif<<<dim3(2048), dim3(256), 0, stream>>>(SQ, KV, SA);
  gemm_p_bn<<<dim3(8, 2, 64), dim3(256), 0, stream>>>(SA, pw, BNS, Y);
  lif_out<<<dim3(4096), dim3(256), 0, stream>>>(Y, out);
}

// Round 2
// 490.714 us; speedup vs baseline: 1.5083x; 1.5083x over previous
//
#include <hip/hip_runtime.h>
#include <stdint.h>

typedef unsigned int u32;
typedef unsigned short ushort_t;

#define T_ 4
#define B_ 16
#define C_ 256
#define N_ 1024
#define CN (C_ * N_)                 /* 262144 */
#define M_ELEMS (64 * C_ * N_)       /* 16777216 elems per [TB,C,N] tensor */

/* workspace byte offsets (ws >= ~138 MB; previously used 270 MB OK) */
#define OFF_S    0ull                          /* SQ,SK,SV u8: 3*16.7MB; later aliased by YP (64MB) */
#define OFF_YP   0ull                          /* fp32 [64][256][1024] = 64MB, live after spikes dead */
#define OFF_XC   67108864ull                   /* Xc bf16 [64 tb][16 slab][1024 n][32 k] = 64MB; later aliased by Sc */
#define OFF_SC   67108864ull                   /* Sc bf16 [64 tb][8 kb][1024 n][32 k] = 32MB */
#define OFF_KV   134217728ull                  /* fp32 [64][8][32][32] = 2MB */
#define OFF_BNS  136314880ull                  /* 8KB */
#define OFF_WC   136323072ull                  /* Wc bf16 [3][256][768] = 1.125MB */
#define OFF_WPC  137502720ull                  /* Wpc bf16 [256][512] = 256KB */

typedef __attribute__((ext_vector_type(8))) short bf16x8;
typedef __attribute__((ext_vector_type(4))) float f32x4;

__device__ __forceinline__ ushort_t f2bf(float f) {
  u32 u = __float_as_uint(f);
  u32 r = (u + 0x7FFFu + ((u >> 16) & 1u)) >> 16;
  return (ushort_t)r;
}
__device__ __forceinline__ float bf2f(ushort_t h) { return __uint_as_float((u32)h << 16); }

__device__ __forceinline__ void async_copy16(const void* g, void* l) {
  __builtin_amdgcn_global_load_lds(
      (const __attribute__((address_space(1))) u32*)g,
      (__attribute__((address_space(3))) u32*)l, 16, 0, 0);
}

/* ---- BN coefficient prep (unchanged) ---- */
__global__ void bn_prep(const float* __restrict__ qg, const float* __restrict__ qb2, const float* __restrict__ qm, const float* __restrict__ qv,
                        const float* __restrict__ kg, const float* __restrict__ kb, const float* __restrict__ km, const float* __restrict__ kvv,
                        const float* __restrict__ vg, const float* __restrict__ vb, const float* __restrict__ vm, const float* __restrict__ vv,
                        const float* __restrict__ pbias,
                        const float* __restrict__ pg, const float* __restrict__ pbt, const float* __restrict__ pm, const float* __restrict__ pv,
                        float* __restrict__ bns) {
  int i = threadIdx.x;  /* 1024 threads */
  int br = i >> 8, c = i & 255;
  const float *g, *bt, *m, *v;
  float bias = 0.f;
  if (br == 0)      { g = qg; bt = qb2; m = qm; v = qv; }
  else if (br == 1) { g = kg; bt = kb;  m = km; v = kvv; }
  else if (br == 2) { g = vg; bt = vb;  m = vm; v = vv; }
  else              { g = pg; bt = pbt; m = pm; v = pv; bias = pbias[c]; }
  float sc = g[c] / sqrtf(v[c] + 1e-5f);
  bns[2 * i] = sc;
  bns[2 * i + 1] = bt[c] + (bias - m[c]) * sc;
}

/* ---- split weights to bf16 hi/lo. Wc[br][256][768] = [hi|lo|hi]; Wpc[256][512] = [hi|lo] ---- */
__global__ __launch_bounds__(256) void convert_w(const float* __restrict__ qw, const float* __restrict__ kw,
                                                 const float* __restrict__ vw, const float* __restrict__ pw,
                                                 ushort_t* __restrict__ Wc, ushort_t* __restrict__ Wpc) {
  int id = blockIdx.x * 256 + threadIdx.x;   /* 4*65536 */
  int br = id >> 16, o = (id >> 8) & 255, c = id & 255;
  const float* w = (br == 0) ? qw : (br == 1) ? kw : (br == 2) ? vw : pw;
  float f = w[o * 256 + c];
  ushort_t hi = f2bf(f);
  ushort_t lo = f2bf(f - bf2f(hi));
  if (br < 3) {
    ushort_t* d = Wc + (size_t)br * 196608 + (size_t)o * 768 + c;
    d[0] = hi; d[256] = lo; d[512] = hi;
  } else {
    ushort_t* d = Wpc + (size_t)o * 512 + c;
    d[0] = hi; d[256] = lo;
  }
}

/* ---- x fp32 [tb][256 c][1024 n] -> Xc bf16 [tb][16 slab][1024 n][32 k]; slab kb<8 = hi, 8+kb = lo ---- */
__global__ __launch_bounds__(256) void convert_x(const float* __restrict__ x, ushort_t* __restrict__ Xc) {
  __shared__ ushort_t hi[32][260];
  __shared__ ushort_t lo[32][260];
  int bid = blockIdx.x;
  int nc = bid & 3, kb = (bid >> 2) & 7, tb = bid >> 5;
  int t = threadIdx.x;
  int n0 = nc * 256;
  const float* xb = x + (size_t)tb * CN + (size_t)(kb * 32) * N_ + n0;
#pragma unroll
  for (int p = 0; p < 8; ++p) {
    int k = p * 4 + (t >> 6);
    int n4 = (t & 63) * 4;
    float4 v = *(const float4*)&xb[(size_t)k * N_ + n4];
    ushort_t h0 = f2bf(v.x), h1 = f2bf(v.y), h2 = f2bf(v.z), h3 = f2bf(v.w);
    short4 hv = make_short4((short)h0, (short)h1, (short)h2, (short)h3);
    short4 lv = make_short4((short)f2bf(v.x - bf2f(h0)), (short)f2bf(v.y - bf2f(h1)),
                            (short)f2bf(v.z - bf2f(h2)), (short)f2bf(v.w - bf2f(h3)));
    *(short4*)&hi[k][n4] = hv;
    *(short4*)&lo[k][n4] = lv;
  }
  __syncthreads();
  ushort_t* Hs = Xc + ((size_t)(tb * 16 + kb) * 1024 + n0) * 32;
  ushort_t* Ls = Xc + ((size_t)(tb * 16 + 8 + kb) * 1024 + n0) * 32;
  int kq = t & 3;
#pragma unroll
  for (int q = 0; q < 4; ++q) {
    int n = q * 64 + (t >> 2);
    u32 a0 = (u32)hi[kq * 8 + 0][n] | ((u32)hi[kq * 8 + 1][n] << 16);
    u32 a1 = (u32)hi[kq * 8 + 2][n] | ((u32)hi[kq * 8 + 3][n] << 16);
    u32 a2 = (u32)hi[kq * 8 + 4][n] | ((u32)hi[kq * 8 + 5][n] << 16);
    u32 a3 = (u32)hi[kq * 8 + 6][n] | ((u32)hi[kq * 8 + 7][n] << 16);
    *(uint4*)(Hs + (size_t)n * 32 + kq * 8) = make_uint4(a0, a1, a2, a3);
    u32 b0 = (u32)lo[kq * 8 + 0][n] | ((u32)lo[kq * 8 + 1][n] << 16);
    u32 b1 = (u32)lo[kq * 8 + 2][n] | ((u32)lo[kq * 8 + 3][n] << 16);
    u32 b2 = (u32)lo[kq * 8 + 4][n] | ((u32)lo[kq * 8 + 5][n] << 16);
    u32 b3 = (u32)lo[kq * 8 + 6][n] | ((u32)lo[kq * 8 + 7][n] << 16);
    *(uint4*)(Ls + (size_t)n * 32 + kq * 8) = make_uint4(b0, b1, b2, b3);
  }
}

/* ---- fused q/k/v MFMA GEMM (K'=768 bf16-split) + BN + LIF -> u8 spikes.
   grid (8 nt, 6 mt, 16 b); block 256 = 4 waves; tile 128x128; wave 64x64 = 4x4 frags 16x16x32 ---- */
__global__ __launch_bounds__(256, 2) void gemm_qkv_lif(
    const ushort_t* __restrict__ Wc, const ushort_t* __restrict__ Xc,
    const float* __restrict__ bns, uint8_t* __restrict__ S) {
  __shared__ ushort_t Al[128 * 32];
  __shared__ ushort_t Bl[128 * 32];
  const int nt = blockIdx.x, mt = blockIdx.y, b = blockIdx.z;
  const int br = mt >> 1, rh = mt & 1;
  const ushort_t* Ab = Wc + (size_t)br * 196608 + (size_t)(rh * 128) * 768;
  const int tid = threadIdx.x;
  const int lane = tid & 63;
  const int quad = lane >> 4, r = lane & 15;
  const int w = tid >> 6;
  const int moff = (w & 1) * 64, noff = (w >> 1) * 64;
  const int c0 = tid, c1 = tid + 256;   /* staging chunk ids */

  float mem[16][4];
#pragma unroll
  for (int f = 0; f < 16; ++f)
#pragma unroll
    for (int rg = 0; rg < 4; ++rg) mem[f][rg] = 0.f;

  for (int t = 0; t < 4; ++t) {
    f32x4 acc[16];
#pragma unroll
    for (int f = 0; f < 16; ++f) acc[f] = (f32x4){0.f, 0.f, 0.f, 0.f};
    const ushort_t* Xtb = Xc + (size_t)(t * 16 + b) * 16 * 32768 + (size_t)(nt * 128) * 32;
    for (int kb = 0; kb < 24; ++kb) {
      const int kbm = (kb < 8) ? kb : kb - 8;
      const ushort_t* Acol = Ab + kb * 32;
      async_copy16(Acol + (size_t)(c0 >> 2) * 768 + (c0 & 3) * 8, &Al[c0 * 8]);
      async_copy16(Acol + (size_t)(c1 >> 2) * 768 + (c1 & 3) * 8, &Al[c1 * 8]);
      const ushort_t* Bb = Xtb + (size_t)kbm * 32768;
      async_copy16(Bb + c0 * 8, &Bl[c0 * 8]);
      async_copy16(Bb + c1 * 8, &Bl[c1 * 8]);
      __syncthreads();
      bf16x8 a0 = *(const bf16x8*)&Al[(moff + 0 * 16 + r) * 32 + quad * 8];
      bf16x8 a1 = *(const bf16x8*)&Al[(moff + 1 * 16 + r) * 32 + quad * 8];
      bf16x8 a2 = *(const bf16x8*)&Al[(moff + 2 * 16 + r) * 32 + quad * 8];
      bf16x8 a3 = *(const bf16x8*)&Al[(moff + 3 * 16 + r) * 32 + quad * 8];
      bf16x8 b0 = *(const bf16x8*)&Bl[(noff + 0 * 16 + r) * 32 + quad * 8];
      bf16x8 b1 = *(const bf16x8*)&Bl[(noff + 1 * 16 + r) * 32 + quad * 8];
      bf16x8 b2 = *(const bf16x8*)&Bl[(noff + 2 * 16 + r) * 32 + quad * 8];
      bf16x8 b3 = *(const bf16x8*)&Bl[(noff + 3 * 16 + r) * 32 + quad * 8];
      acc[0]  = __builtin_amdgcn_mfma_f32_16x16x32_bf16(a0, b0, acc[0],  0, 0, 0);
      acc[1]  = __builtin_amdgcn_mfma_f32_16x16x32_bf16(a0, b1, acc[1],  0, 0, 0);
      acc[2]  = __builtin_amdgcn_mfma_f32_16x16x32_bf16(a0, b2, acc[2],  0, 0, 0);
      acc[3]  = __builtin_amdgcn_mfma_f32_16x16x32_bf16(a0, b3, acc[3],  0, 0, 0);
      acc[4]  = __builtin_amdgcn_mfma_f32_16x16x32_bf16(a1, b0, acc[4],  0, 0, 0);
      acc[5]  = __builtin_amdgcn_mfma_f32_16x16x32_bf16(a1, b1, acc[5],  0, 0, 0);
      acc[6]  = __builtin_amdgcn_mfma_f32_16x16x32_bf16(a1, b2, acc[6],  0, 0, 0);
      acc[7]  = __builtin_amdgcn_mfma_f32_16x16x32_bf16(a1, b3, acc[7],  0, 0, 0);
      acc[8]  = __builtin_amdgcn_mfma_f32_16x16x32_bf16(a2, b0, acc[8],  0, 0, 0);
      acc[9]  = __builtin_amdgcn_mfma_f32_16x16x32_bf16(a2, b1, acc[9],  0, 0, 0);
      acc[10] = __builtin_amdgcn_mfma_f32_16x16x32_bf16(a2, b2, acc[10], 0, 0, 0);
      acc[11] = __builtin_amdgcn_mfma_f32_16x16x32_bf16(a2, b3, acc[11], 0, 0, 0);
      acc[12] = __builtin_amdgcn_mfma_f32_16x16x32_bf16(a3, b0, acc[12], 0, 0, 0);
      acc[13] = __builtin_amdgcn_mfma_f32_16x16x32_bf16(a3, b1, acc[13], 0, 0, 0);
      acc[14] = __builtin_amdgcn_mfma_f32_16x16x32_bf16(a3, b2, acc[14], 0, 0, 0);
      acc[15] = __builtin_amdgcn_mfma_f32_16x16x32_bf16(a3, b3, acc[15], 0, 0, 0);
      __syncthreads();
    }
    /* epilogue: BN + LIF step + spike byte store */
    uint8_t* Sb = S + (size_t)br * M_ELEMS + (size_t)(t * 16 + b) * CN;
#pragma unroll
    for (int i = 0; i < 4; ++i) {
#pragma unroll
      for (int rg = 0; rg < 4; ++rg) {
        int c = rh * 128 + moff + i * 16 + quad * 4 + rg;
        float sc = bns[2 * (br * 256 + c)];
        float sh = bns[2 * (br * 256 + c) + 1];
        uint8_t* row = Sb + (size_t)c * N_ + nt * 128 + noff + r;
#pragma unroll
        for (int j = 0; j < 4; ++j) {
          float y = acc[i * 4 + j][rg] * sc + sh;
          float m = mem[i * 4 + j][rg];
          m += (y - m) * 0.5f;
          uint8_t s = (m >= 1.0f) ? 1 : 0;
          row[j * 16] = s;
          mem[i * 4 + j][rg] = s ? 0.f : m;
        }
      }
    }
  }
}

/* ---- v spikes [T,B,C,N] u8 -> d_out v fp32 [T,B,H,N,D] (unchanged) ---- */
__global__ __launch_bounds__(256) void transpose_v(const uint8_t* __restrict__ SV, float* __restrict__ vout) {
  size_t o4 = ((size_t)blockIdx.x * 256 + threadIdx.x) * 4;
  int dd = (int)(o4 & 31);
  int n = (int)((o4 >> 5) & 1023);
  int h = (int)((o4 >> 15) & 7);
  int tb = (int)(o4 >> 18);
  const uint8_t* src = SV + (size_t)tb * CN + (size_t)(h * 32 + dd) * N_ + n;
  *(float4*)(vout + o4) = make_float4((float)src[0], (float)src[(size_t)N_],
                                      (float)src[2 * (size_t)N_], (float)src[3 * (size_t)N_]);
}

/* ---- kv gram (unchanged) ---- */
__global__ __launch_bounds__(256) void kv_gram(const uint8_t* __restrict__ SK,
                                               const uint8_t* __restrict__ SV,
                                               float* __restrict__ KV) {
  __shared__ uint8_t Ks[32 * 132];
  __shared__ uint8_t Vs[32 * 132];
  const int tb = blockIdx.x >> 3, h = blockIdx.x & 7;
  const uint8_t* K = SK + (size_t)tb * CN + (size_t)h * 32 * N_;
  const uint8_t* V = SV + (size_t)tb * CN + (size_t)h * 32 * N_;
  const int tid = threadIdx.x;
  const int dd = tid >> 3, e0 = (tid & 7) * 4;
  const int lr = tid >> 3, lc = (tid & 7) * 16;
  float a0 = 0.f, a1 = 0.f, a2 = 0.f, a3 = 0.f;
  for (int n0 = 0; n0 < N_; n0 += 128) {
    uint4 kk4 = *(const uint4*)(K + (size_t)lr * N_ + n0 + lc);
    uint4 vv4 = *(const uint4*)(V + (size_t)lr * N_ + n0 + lc);
    unsigned* Kw = (unsigned*)(Ks + lr * 132 + lc);
    unsigned* Vw = (unsigned*)(Vs + lr * 132 + lc);
    Kw[0] = kk4.x; Kw[1] = kk4.y; Kw[2] = kk4.z; Kw[3] = kk4.w;
    Vw[0] = vv4.x; Vw[1] = vv4.y; Vw[2] = vv4.z; Vw[3] = vv4.w;
    __syncthreads();
    for (int n = 0; n < 128; ++n) {
      float kf = (float)Ks[dd * 132 + n];
      a0 += kf * (float)Vs[(e0 + 0) * 132 + n];
      a1 += kf * (float)Vs[(e0 + 1) * 132 + n];
      a2 += kf * (float)Vs[(e0 + 2) * 132 + n];
      a3 += kf * (float)Vs[(e0 + 3) * 132 + n];
    }
    __syncthreads();
  }
  float* o = KV + (size_t)(tb * 8 + h) * 1024 + dd * 32 + e0;
  o[0] = a0; o[1] = a1; o[2] = a2; o[3] = a3;
}

/* ---- fused attn + LIF(0.5) -> bf16 spikes Sc [tb][8 kb][1024 n][32 k] ---- */
__global__ __launch_bounds__(256) void attn_lif(const uint8_t* __restrict__ SQ,
                                                const float* __restrict__ KV,
                                                ushort_t* __restrict__ Sc) {
  __shared__ float kvs[1024];
  const int bid = blockIdx.x;
  const int nb = bid & 15, h = (bid >> 4) & 7, b = bid >> 7;
  const int n0 = nb * 64;
  const int tid = threadIdx.x;
  const int nl = tid & 63, eg = tid >> 6;
  float mem[8];
#pragma unroll
  for (int j = 0; j < 8; ++j) mem[j] = 0.f;
  for (int t = 0; t < 4; ++t) {
    const float* kvp = KV + (size_t)((t * B_ + b) * 8 + h) * 1024;
    *(float4*)&kvs[tid * 4] = *(const float4*)&kvp[tid * 4];
    __syncthreads();
    const uint8_t* q = SQ + (size_t)(t * B_ + b) * CN + (size_t)h * 32 * N_ + n0 + nl;
    float val[8];
#pragma unroll
    for (int j = 0; j < 8; ++j) val[j] = 0.f;
#pragma unroll 4
    for (int dd = 0; dd < 32; ++dd) {
      float qv = (float)q[(size_t)dd * N_];
#pragma unroll
      for (int j = 0; j < 8; ++j) val[j] += qv * kvs[dd * 32 + eg * 8 + j];
    }
    ushort_t pk[8];
#pragma unroll
    for (int j = 0; j < 8; ++j) {
      float a = val[j] * 0.125f;
      mem[j] += (a - mem[j]) * 0.5f;
      int s = (mem[j] >= 0.5f);
      pk[j] = s ? (ushort_t)0x3F80 : (ushort_t)0;
      if (s) mem[j] = 0.f;
    }
    uint4 o;
    o.x = (u32)pk[0] | ((u32)pk[1] << 16);
    o.y = (u32)pk[2] | ((u32)pk[3] << 16);
    o.z = (u32)pk[4] | ((u32)pk[5] << 16);
    o.w = (u32)pk[6] | ((u32)pk[7] << 16);
    *(uint4*)(Sc + ((size_t)((t * B_ + b) * 8 + h) * 1024 + n0 + nl) * 32 + eg * 8) = o;
    __syncthreads();
  }
}

/* ---- p projection MFMA GEMM (K'=512) + BN -> YP fp32. grid (8 nt, 2 mt, 64 tb) ---- */
__global__ __launch_bounds__(256, 3) void gemm_p_mfma(
    const ushort_t* __restrict__ Wpc, const ushort_t* __restrict__ Sc,
    const float* __restrict__ bns, float* __restrict__ YP) {
  __shared__ ushort_t Al[128 * 32];
  __shared__ ushort_t Bl[128 * 32];
  const int nt = blockIdx.x, mt = blockIdx.y, tb = blockIdx.z;
  const ushort_t* Ab = Wpc + (size_t)(mt * 128) * 512;
  const int tid = threadIdx.x;
  const int lane = tid & 63;
  const int quad = lane >> 4, r = lane & 15;
  const int w = tid >> 6;
  const int moff = (w & 1) * 64, noff = (w >> 1) * 64;
  const int c0 = tid, c1 = tid + 256;
  f32x4 acc[16];
#pragma unroll
  for (int f = 0; f < 16; ++f) acc[f] = (f32x4){0.f, 0.f, 0.f, 0.f};
  const ushort_t* Stb = Sc + (size_t)tb * 8 * 32768 + (size_t)(nt * 128) * 32;
  for (int kb = 0; kb < 16; ++kb) {
    const int kbm = (kb < 8) ? kb : kb - 8;
    const ushort_t* Acol = Ab + kb * 32;
    async_copy16(Acol + (size_t)(c0 >> 2) * 512 + (c0 & 3) * 8, &Al[c0 * 8]);
    async_copy16(Acol + (size_t)(c1 >> 2) * 512 + (c1 & 3) * 8, &Al[c1 * 8]);
    const ushort_t* Bb = Stb + (size_t)kbm * 32768;
    async_copy16(Bb + c0 * 8, &Bl[c0 * 8]);
    async_copy16(Bb + c1 * 8, &Bl[c1 * 8]);
    __syncthreads();
    bf16x8 a0 = *(const bf16x8*)&Al[(moff + 0 * 16 + r) * 32 + quad * 8];
    bf16x8 a1 = *(const bf16x8*)&Al[(moff + 1 * 16 + r) * 32 + quad * 8];
    bf16x8 a2 = *(const bf16x8*)&Al[(moff + 2 * 16 + r) * 32 + quad * 8];
    bf16x8 a3 = *(const bf16x8*)&Al[(moff + 3 * 16 + r) * 32 + quad * 8];
    bf16x8 b0 = *(const bf16x8*)&Bl[(noff + 0 * 16 + r) * 32 + quad * 8];
    bf16x8 b1 = *(const bf16x8*)&Bl[(noff + 1 * 16 + r) * 32 + quad * 8];
    bf16x8 b2 = *(const bf16x8*)&Bl[(noff + 2 * 16 + r) * 32 + quad * 8];
    bf16x8 b3 = *(const bf16x8*)&Bl[(noff + 3 * 16 + r) * 32 + quad * 8];
    acc[0]  = __builtin_amdgcn_mfma_f32_16x16x32_bf16(a0, b0, acc[0],  0, 0, 0);
    acc[1]  = __builtin_amdgcn_mfma_f32_16x16x32_bf16(a0, b1, acc[1],  0, 0, 0);
    acc[2]  = __builtin_amdgcn_mfma_f32_16x16x32_bf16(a0, b2, acc[2],  0, 0, 0);
    acc[3]  = __builtin_amdgcn_mfma_f32_16x16x32_bf16(a0, b3, acc[3],  0, 0, 0);
    acc[4]  = __builtin_amdgcn_mfma_f32_16x16x32_bf16(a1, b0, acc[4],  0, 0, 0);
    acc[5]  = __builtin_amdgcn_mfma_f32_16x16x32_bf16(a1, b1, acc[5],  0, 0, 0);
    acc[6]  = __builtin_amdgcn_mfma_f32_16x16x32_bf16(a1, b2, acc[6],  0, 0, 0);
    acc[7]  = __builtin_amdgcn_mfma_f32_16x16x32_bf16(a1, b3, acc[7],  0, 0, 0);
    acc[8]  = __builtin_amdgcn_mfma_f32_16x16x32_bf16(a2, b0, acc[8],  0, 0, 0);
    acc[9]  = __builtin_amdgcn_mfma_f32_16x16x32_bf16(a2, b1, acc[9],  0, 0, 0);
    acc[10] = __builtin_amdgcn_mfma_f32_16x16x32_bf16(a2, b2, acc[10], 0, 0, 0);
    acc[11] = __builtin_amdgcn_mfma_f32_16x16x32_bf16(a2, b3, acc[11], 0, 0, 0);
    acc[12] = __builtin_amdgcn_mfma_f32_16x16x32_bf16(a3, b0, acc[12], 0, 0, 0);
    acc[13] = __builtin_amdgcn_mfma_f32_16x16x32_bf16(a3, b1, acc[13], 0, 0, 0);
    acc[14] = __builtin_amdgcn_mfma_f32_16x16x32_bf16(a3, b2, acc[14], 0, 0, 0);
    acc[15] = __builtin_amdgcn_mfma_f32_16x16x32_bf16(a3, b3, acc[15], 0, 0, 0);
    __syncthreads();
  }
  float* Yb = YP + (size_t)tb * CN;
#pragma unroll
  for (int i = 0; i < 4; ++i) {
#pragma unroll
    for (int rg = 0; rg < 4; ++rg) {
      int c = mt * 128 + moff + i * 16 + quad * 4 + rg;
      float sc = bns[2 * (768 + c)];
      float sh = bns[2 * (768 + c) + 1];
      float* row = Yb + (size_t)c * N_ + nt * 128 + noff + r;
#pragma unroll
      for (int j = 0; j < 4; ++j) row[j * 16] = acc[i * 4 + j][rg] * sc + sh;
    }
  }
}

/* ---- final LIF (vth=1.0) (unchanged) ---- */
__global__ __launch_bounds__(256) void lif_out(const float* __restrict__ YP, float* __restrict__ out) {
  size_t e4 = ((size_t)blockIdx.x * 256 + threadIdx.x) * 4;
  float m0 = 0.f, m1 = 0.f, m2 = 0.f, m3 = 0.f;
#pragma unroll
  for (int t = 0; t < 4; ++t) {
    float4 y = *(const float4*)(YP + (size_t)t * (B_ * CN) + e4);
    m0 += (y.x - m0) * 0.5f;
    m1 += (y.y - m1) * 0.5f;
    m2 += (y.z - m2) * 0.5f;
    m3 += (y.w - m3) * 0.5f;
    float s0 = (m0 >= 1.0f) ? 1.f : 0.f;
    float s1 = (m1 >= 1.0f) ? 1.f : 0.f;
    float s2 = (m2 >= 1.0f) ? 1.f : 0.f;
    float s3 = (m3 >= 1.0f) ? 1.f : 0.f;
    *(float4*)(out + (size_t)t * (B_ * CN) + e4) = make_float4(s0, s1, s2, s3);
    m0 *= (1.f - s0);
    m1 *= (1.f - s1);
    m2 *= (1.f - s2);
    m3 *= (1.f - s3);
  }
}

extern "C" void kernel_launch(void* const* d_in, const int* in_sizes, int n_in,
                              void* d_out, int out_size, void* d_ws, size_t ws_size,
                              hipStream_t stream) {
  const float* x   = (const float*)d_in[0];
  const float* qw  = (const float*)d_in[2];
  const float* qg  = (const float*)d_in[3];
  const float* qb  = (const float*)d_in[4];
  const float* qm  = (const float*)d_in[5];
  const float* qv  = (const float*)d_in[6];
  const float* kw  = (const float*)d_in[7];
  const float* kg  = (const float*)d_in[8];
  const float* kb  = (const float*)d_in[9];
  const float* km  = (const float*)d_in[10];
  const float* kvv = (const float*)d_in[11];
  const float* vw  = (const float*)d_in[12];
  const float* vg  = (const float*)d_in[13];
  const float* vb  = (const float*)d_in[14];
  const float* vm  = (const float*)d_in[15];
  const float* vv  = (const float*)d_in[16];
  const float* pw  = (const float*)d_in[17];
  const float* pb  = (const float*)d_in[18];
  const float* pg  = (const float*)d_in[19];
  const float* pbt = (const float*)d_in[20];
  const float* pm  = (const float*)d_in[21];
  const float* pv  = (const float*)d_in[22];

  float* out = (float*)d_out;
  float* vout = out + M_ELEMS;

  uint8_t* ws = (uint8_t*)d_ws;
  uint8_t* S   = ws + OFF_S;          /* SQ | SK | SV */
  float* YP    = (float*)(ws + OFF_YP);
  ushort_t* Xc = (ushort_t*)(ws + OFF_XC);
  ushort_t* Sc = (ushort_t*)(ws + OFF_SC);
  float* KV    = (float*)(ws + OFF_KV);
  float* BNS   = (float*)(ws + OFF_BNS);
  ushort_t* Wc  = (ushort_t*)(ws + OFF_WC);
  ushort_t* Wpc = (ushort_t*)(ws + OFF_WPC);

  bn_prep<<<dim3(1), dim3(1024), 0, stream>>>(qg, qb, qm, qv, kg, kb, km, kvv,
                                              vg, vb, vm, vv, pb, pg, pbt, pm, pv, BNS);
  convert_w<<<dim3(1024), dim3(256), 0, stream>>>(qw, kw, vw, pw, Wc, Wpc);
  convert_x<<<dim3(2048), dim3(256), 0, stream>>>(x, Xc);
  gemm_qkv_lif<<<dim3(8, 6, 16), dim3(256), 0, stream>>>(Wc, Xc, BNS, S);
  transpose_v<<<dim3(16384), dim3(256), 0, stream>>>(S + 2ull * M_ELEMS, vout);
  kv_gram<<<dim3(512), dim3(256), 0, stream>>>(S + 1ull * M_ELEMS, S + 2ull * M_ELEMS, KV);
  attn_lif<<<dim3(2048), dim3(256), 0, stream>>>(S, KV, Sc);
  gemm_p_mfma<<<dim3(8, 2, 64), dim3(256), 0, stream>>>(Wpc, Sc, BNS, YP);
  lif_out<<<dim3(4096), dim3(256), 0, stream>>>(YP, out);
}